// Round 6
// baseline (408.513 us; speedup 1.0000x reference)
//
#include <hip/hip_runtime.h>

// ---------------- problem constants ----------------
#define B_    4
#define CI_   2
#define H_    48
#define W_    48
#define T_    96
#define CO_   64
#define XO_   23
#define NSITE 529         // 23*23
#define TP_   145         // output time steps (29*5)
#define TPAD_ 200         // padded LDS time window per row (max read idx 194)
#define NTAP_ 18          // CI*3*3
#define THETA_ 5.4f
#define FODEP_ 48
#define WCAP_  265        // ceil(0.5*529)
#define NOUT4 (19636480 / 4)

// ws layout (floats)
#define WS_WKF 0                      // [64][18][48] = 55296 floats
#define WS_KS  55296                  // [64][18] ints
#define WS_M   (55296 + 1152)         // [4][145][529] floats
#define WS_A   (WS_M + 306820)        // [4][145][529] ints

// ---------------- kernel: temporal kernel synthesis + start-index table ----
__global__ void k_wk(const float* __restrict__ weight, float* __restrict__ wkf,
                     int* __restrict__ kstab) {
    int idx = blockIdx.x * 256 + threadIdx.x;       // (o, tap)
    if (idx >= CO_ * NTAP_) return;
    int o = idx / NTAP_, tap = idx % NTAP_;
    int i = tap / 9, kx = (tap % 9) / 3, ky = tap % 3;
    float w = weight[((o * CI_ + i) * 3 + kx) * 3 + ky];
    int ktlo = 48;
    for (int kt = 0; kt < 48; ++kt) {
        float j = (float)(47 - kt);
        float v = fmaxf(0.0f, fminf(j * (1.0f / 16.0f), 1.5f * w - j * (1.0f / 32.0f)));
        wkf[idx * 48 + kt] = v;
        if (v > 0.0f && ktlo == 48) ktlo = kt;
    }
    kstab[idx] = (ktlo >= 48) ? 48 : (ktlo - ktlo % 5);
}

// 5-step FIR segment with 10-register shift window and distance-25 prefetch.
// entry invariant: w_q == s[t0 + S + q], q = 0..9. exit: w_q == s[t0 + S+5 + q].
// per-acc accumulation order is ascending kt (bit-identical to prior rounds).
#define SEGP(S) \
    { float k0 = wrow[(S)],   k1 = wrow[(S)+1], k2 = wrow[(S)+2], \
            k3 = wrow[(S)+3], k4 = wrow[(S)+4]; \
      float n0 = sptr[(S)+10], n1 = sptr[(S)+11], n2 = sptr[(S)+12], \
            n3 = sptr[(S)+13], n4 = sptr[(S)+14]; \
      a0 = fmaf(k0, w0, a0); a1 = fmaf(k0, w1, a1); a2 = fmaf(k0, w2, a2); \
      a3 = fmaf(k0, w3, a3); a4 = fmaf(k0, w4, a4); \
      a0 = fmaf(k1, w1, a0); a1 = fmaf(k1, w2, a1); a2 = fmaf(k1, w3, a2); \
      a3 = fmaf(k1, w4, a3); a4 = fmaf(k1, w5, a4); \
      a0 = fmaf(k2, w2, a0); a1 = fmaf(k2, w3, a1); a2 = fmaf(k2, w4, a2); \
      a3 = fmaf(k2, w5, a3); a4 = fmaf(k2, w6, a4); \
      a0 = fmaf(k3, w3, a0); a1 = fmaf(k3, w4, a1); a2 = fmaf(k3, w5, a2); \
      a3 = fmaf(k3, w6, a3); a4 = fmaf(k3, w7, a4); \
      a0 = fmaf(k4, w4, a0); a1 = fmaf(k4, w5, a1); a2 = fmaf(k4, w6, a2); \
      a3 = fmaf(k4, w7, a3); a4 = fmaf(k4, w8, a4); \
      w0 = w5; w1 = w6; w2 = w7; w3 = w8; w4 = w9; \
      w5 = n0; w6 = n1; w7 = n2; w8 = n3; w9 = n4; }

// ---------------- kernel: conv + channel max/argmax (+ output zero-fill) ----
// block = (b, x, ychunk of 2). 512 threads = 8 waves; wave wq owns channels
// [8wq, 8wq+8) (wave-uniform o => scalar k loads). lane = 2dy x 32tg, t_tile=5.
__launch_bounds__(512, 8)
__global__ void k_conv(const float* __restrict__ in, const float* __restrict__ wkf,
                       const int* __restrict__ kstab, const float* __restrict__ bias,
                       float* __restrict__ m_out, int* __restrict__ a_out,
                       float4* __restrict__ out4) {
    __shared__ __align__(16) union {
        float sp[30][TPAD_];                                   // 24000 B
        struct { float m[8][64][5]; int a[8][64][5]; } red;    // 20480 B
    } u;

    int bid = blockIdx.x;
    int b  = bid / (XO_ * 12);
    int r  = bid % (XO_ * 12);
    int x  = r / 12;
    int y0 = (r % 12) * 2;
    int tid  = threadIdx.x;
    int lane = tid & 63;
    int dy   = lane >> 5;                 // 0/1
    int tg   = lane & 31;                 // t-group
    int t0   = (tg < 29) ? tg * 5 : 140;  // clamp garbage lanes in-bounds
    int y    = y0 + dy;
    bool valid = (y < XO_) && (tg < 29);

    // fold-in: zero the spike output (fire-and-forget stores, hidden by compute)
    {
        int stride = gridDim.x * blockDim.x;                   // 565248
        float4 z = make_float4(0.f, 0.f, 0.f, 0.f);
        for (int i2 = bid * blockDim.x + tid; i2 < NOUT4; i2 += stride) out4[i2] = z;
    }

    // zero pad (float4) then fill rows. row = (i*3+kx)*5 + c, col = 2*y0+c
    for (int q = tid; q < 30 * TPAD_ / 4; q += 512)
        ((float4*)u.sp)[q] = make_float4(0.f, 0.f, 0.f, 0.f);
    __syncthreads();
    for (int q = tid; q < 30 * 24; q += 512) {
        int row = q / 24, f4 = q % 24;
        int c = row % 5, rr = row / 5;
        int kx = rr % 3, i = rr / 3;
        int col = 2 * y0 + c;
        if (col < W_) {
            const float4* src = (const float4*)(in +
                ((((size_t)b * CI_ + i) * H_ + (2 * x + kx)) * W_ + col) * T_);
            *(float4*)(&u.sp[row][48 + f4 * 4]) = src[f4];
        }
    }
    __syncthreads();

    float mbest[5];
    int   abest[5];
#pragma unroll
    for (int j = 0; j < 5; ++j) { mbest[j] = -1e30f; abest[j] = 0; }

    int wq    = __builtin_amdgcn_readfirstlane(tid >> 6);
    int obase = wq * 8;
    const float* sbase = &u.sp[0][0] + 2 * dy * TPAD_ + t0;   // row(tap0) = 2dy

#pragma unroll 1
    for (int oi = 0; oi < 8; ++oi) {
        int o = obase + oi;
        const int* ksrow = kstab + o * NTAP_;
        const float* wrow = wkf + o * (NTAP_ * 48);           // advanced per tap
        const float* sptr = sbase;                            // advanced per tap
        int ky3 = 0;
        float a0 = 0.f, a1 = 0.f, a2 = 0.f, a3 = 0.f, a4 = 0.f;
        int ks_next = ksrow[0];
#pragma unroll 1
        for (int tap = 0; tap < NTAP_; ++tap) {
            int ks = __builtin_amdgcn_readfirstlane(ks_next);
            if (tap + 1 < NTAP_) ks_next = ksrow[tap + 1];    // prefetch next tap
            if (ks < 48) {
                // init 10-reg window at (uniform) ks
                const float* sk = sptr + ks;
                float w0 = sk[0], w1 = sk[1], w2 = sk[2], w3 = sk[3], w4 = sk[4],
                      w5 = sk[5], w6 = sk[6], w7 = sk[7], w8 = sk[8], w9 = sk[9];
                if (ks <= 0)  SEGP(0)
                if (ks <= 5)  SEGP(5)
                if (ks <= 10) SEGP(10)
                if (ks <= 15) SEGP(15)
                if (ks <= 20) SEGP(20)
                if (ks <= 25) SEGP(25)
                if (ks <= 30) SEGP(30)
                if (ks <= 35) SEGP(35)
                if (ks <= 40) SEGP(40)
                {   // tail kt = 45, 46 (K[47] == 0 always); w_q == s[t0+45+q]
                    float k45 = wrow[45], k46 = wrow[46];
                    a0 = fmaf(k45, w0, a0); a1 = fmaf(k45, w1, a1); a2 = fmaf(k45, w2, a2);
                    a3 = fmaf(k45, w3, a3); a4 = fmaf(k45, w4, a4);
                    a0 = fmaf(k46, w1, a0); a1 = fmaf(k46, w2, a1); a2 = fmaf(k46, w3, a2);
                    a3 = fmaf(k46, w4, a3); a4 = fmaf(k46, w5, a4);
                }
            }
            // advance pointers: row += 1 (ky++), or += 3 on ky wrap
            wrow += 48;
            if (++ky3 == 3) { ky3 = 0; sptr += 3 * TPAD_; }
            else            { sptr += TPAD_; }
        }
        // incremental max/argmax (strict >, o ascending => smallest o on ties)
        float bo = bias[o];
        float p0 = a0 + bo, p1 = a1 + bo, p2 = a2 + bo, p3 = a3 + bo, p4 = a4 + bo;
        if (p0 > mbest[0]) { mbest[0] = p0; abest[0] = o; }
        if (p1 > mbest[1]) { mbest[1] = p1; abest[1] = o; }
        if (p2 > mbest[2]) { mbest[2] = p2; abest[2] = o; }
        if (p3 > mbest[3]) { mbest[3] = p3; abest[3] = o; }
        if (p4 > mbest[4]) { mbest[4] = p4; abest[4] = o; }
    }

    __syncthreads();   // done reading u.sp — safe to overwrite with u.red
#pragma unroll
    for (int j = 0; j < 5; ++j) { u.red.m[wq][lane][j] = mbest[j]; u.red.a[wq][lane][j] = abest[j]; }
    __syncthreads();
    if (wq == 0 && valid) {
        int site = x * XO_ + y;
#pragma unroll
        for (int j = 0; j < 5; ++j) {
            float mv = u.red.m[0][lane][j];
            int   av = u.red.a[0][lane][j];
#pragma unroll
            for (int w = 1; w < 8; ++w) {
                float m2 = u.red.m[w][lane][j];
                if (m2 > mv) { mv = m2; av = u.red.a[w][lane][j]; }
            }
            size_t off = ((size_t)b * TP_ + (t0 + j)) * NSITE + site;
            m_out[off] = mv;
            a_out[off] = av;
        }
    }
}

// ---------------- kernel: sequential WTA ----------------
// one block per batch, 576 threads (site = tid). coalesced [b][t][site] loads,
// next-t prefetch, 1 barrier/step via double-buffered counts.
__launch_bounds__(576)
__global__ void k_wta(const float* __restrict__ m_in, const int* __restrict__ a_in,
                      float* __restrict__ out) {
    int b = blockIdx.x;
    int tid = threadIdx.x;
    int lane = tid & 63;
    int wid = tid >> 6;                 // 9 waves
    __shared__ int cnts[2][9];

    bool site = (tid < NSITE);
    const float* mb = m_in + (size_t)b * TP_ * NSITE;
    const int*   ab = a_in + (size_t)b * TP_ * NSITE;
    int dep = 0;
    float mv = site ? mb[tid] : 0.f;
    int   av = site ? ab[tid] : 0;

    for (int t = 0; t < TP_; ++t) {
        unsigned long long ball = __ballot(dep != 0);
        if (lane == 0) cnts[t & 1][wid] = __popcll(ball);
        // prefetch next row while the barrier settles
        float mv2 = 0.f; int av2 = 0;
        if (site && t + 1 < TP_) {
            mv2 = mb[(t + 1) * NSITE + tid];
            av2 = ab[(t + 1) * NSITE + tid];
        }
        __syncthreads();
        int tot = 0;
#pragma unroll
        for (int w = 0; w < 9; ++w) tot += cnts[t & 1][w];
        if (site) {
            if ((tot < WCAP_) && (dep == 0) && (mv > THETA_)) {
                out[(((size_t)b * CO_ + av) * NSITE + tid) * TP_ + t] = 1.0f;
                dep = FODEP_ - 1;
            } else {
                dep = dep ? dep - 1 : 0;
            }
        }
        mv = mv2; av = av2;
    }
}

// ---------------- launcher ----------------
extern "C" void kernel_launch(void* const* d_in, const int* in_sizes, int n_in,
                              void* d_out, int out_size, void* d_ws, size_t ws_size,
                              hipStream_t stream) {
    const float* in     = (const float*)d_in[0];
    const float* weight = (const float*)d_in[1];
    const float* bias   = (const float*)d_in[2];
    float* out = (float*)d_out;

    float* wkf   = (float*)d_ws + WS_WKF;
    int*   kstab = (int*)((float*)d_ws + WS_KS);
    float* m     = (float*)d_ws + WS_M;
    int*   a     = (int*)((float*)d_ws + WS_A);

    k_wk<<<(CO_ * NTAP_ + 255) / 256, 256, 0, stream>>>(weight, wkf, kstab);
    k_conv<<<B_ * XO_ * 12, 512, 0, stream>>>(in, wkf, kstab, bias, m, a, (float4*)out);
    k_wta<<<B_, 576, 0, stream>>>(m, a, out);
}

// Round 8
// 368.689 us; speedup vs baseline: 1.1080x; 1.1080x over previous
//
#include <hip/hip_runtime.h>

// ---------------- problem constants ----------------
#define B_    4
#define CI_   2
#define H_    48
#define W_    48
#define T_    96
#define CO_   64
#define XO_   23
#define NSITE 529         // 23*23
#define TP_   145         // output time steps (29*5)
#define TPAD_ 200         // padded LDS time window per row (max read idx 194)
#define NTAP_ 18          // CI*3*3
#define NITEM (B_ * XO_ * 12)   // 1104 site-chunks
#define GRID_ 1024
#define THETA_ 5.4f
#define FODEP_ 48
#define WCAP_  265        // ceil(0.5*529)
#define NOUT4 (19636480 / 4)

// ws layout (floats)
#define WS_WKF 0                      // [64][18][48] = 55296 floats
#define WS_KS  55296                  // [64][18] ints
#define WS_M   (55296 + 1152)         // [4][145][529] floats
#define WS_A   (WS_M + 306820)        // [4][145][529] ints

// ---------------- kernel: temporal kernel synthesis + start-index table ----
// kstab packs: ks (low 6 bits) | parity=(ks/5)&1 << 8  (48 = empty kernel)
__global__ void k_wk(const float* __restrict__ weight, float* __restrict__ wkf,
                     int* __restrict__ kstab) {
    int idx = blockIdx.x * 256 + threadIdx.x;       // (o, tap)
    if (idx >= CO_ * NTAP_) return;
    int o = idx / NTAP_, tap = idx % NTAP_;
    int i = tap / 9, kx = (tap % 9) / 3, ky = tap % 3;
    float w = weight[((o * CI_ + i) * 3 + kx) * 3 + ky];
    int ktlo = 48;
    for (int kt = 0; kt < 48; ++kt) {
        float j = (float)(47 - kt);
        float v = fmaxf(0.0f, fminf(j * (1.0f / 16.0f), 1.5f * w - j * (1.0f / 32.0f)));
        wkf[idx * 48 + kt] = v;
        if (v > 0.0f && ktlo == 48) ktlo = kt;
    }
    if (ktlo >= 48) { kstab[idx] = 48; return; }
    int ks = ktlo - ktlo % 5;
    kstab[idx] = ks | (((ks / 5) & 1) << 8);
}

// ---- two-bank ping-pong FIR segments (zero movs, distance-2-segment prefetch)
// SEGA(S): cur bank = c (c_j == s[t0+S+j]), next = n (n_j == s[t0+S+5+j]).
// each phase reloads its dead cur-register with s[t0+S+10+j].
// FMA order per accumulator: ascending kt — bit-identical across rounds.
#define SEGA(S) \
    { float k0 = wrow[(S)], k1 = wrow[(S)+1], k2 = wrow[(S)+2], \
            k3 = wrow[(S)+3], k4 = wrow[(S)+4]; \
      a0 = fmaf(k0, c0, a0); a1 = fmaf(k0, c1, a1); a2 = fmaf(k0, c2, a2); \
      a3 = fmaf(k0, c3, a3); a4 = fmaf(k0, c4, a4); c0 = sptr[(S)+10]; \
      a0 = fmaf(k1, c1, a0); a1 = fmaf(k1, c2, a1); a2 = fmaf(k1, c3, a2); \
      a3 = fmaf(k1, c4, a3); a4 = fmaf(k1, n0, a4); c1 = sptr[(S)+11]; \
      a0 = fmaf(k2, c2, a0); a1 = fmaf(k2, c3, a1); a2 = fmaf(k2, c4, a2); \
      a3 = fmaf(k2, n0, a3); a4 = fmaf(k2, n1, a4); c2 = sptr[(S)+12]; \
      a0 = fmaf(k3, c3, a0); a1 = fmaf(k3, c4, a1); a2 = fmaf(k3, n0, a2); \
      a3 = fmaf(k3, n1, a3); a4 = fmaf(k3, n2, a4); c3 = sptr[(S)+13]; \
      a0 = fmaf(k4, c4, a0); a1 = fmaf(k4, n0, a1); a2 = fmaf(k4, n1, a2); \
      a3 = fmaf(k4, n2, a3); a4 = fmaf(k4, n3, a4); c4 = sptr[(S)+14]; }

#define SEGB(S) \
    { float k0 = wrow[(S)], k1 = wrow[(S)+1], k2 = wrow[(S)+2], \
            k3 = wrow[(S)+3], k4 = wrow[(S)+4]; \
      a0 = fmaf(k0, n0, a0); a1 = fmaf(k0, n1, a1); a2 = fmaf(k0, n2, a2); \
      a3 = fmaf(k0, n3, a3); a4 = fmaf(k0, n4, a4); n0 = sptr[(S)+10]; \
      a0 = fmaf(k1, n1, a0); a1 = fmaf(k1, n2, a1); a2 = fmaf(k1, n3, a2); \
      a3 = fmaf(k1, n4, a3); a4 = fmaf(k1, c0, a4); n1 = sptr[(S)+11]; \
      a0 = fmaf(k2, n2, a0); a1 = fmaf(k2, n3, a1); a2 = fmaf(k2, n4, a2); \
      a3 = fmaf(k2, c0, a3); a4 = fmaf(k2, c1, a4); n2 = sptr[(S)+12]; \
      a0 = fmaf(k3, n3, a0); a1 = fmaf(k3, n4, a1); a2 = fmaf(k3, c0, a2); \
      a3 = fmaf(k3, c1, a3); a4 = fmaf(k3, c2, a4); n3 = sptr[(S)+13]; \
      a0 = fmaf(k4, n4, a0); a1 = fmaf(k4, c0, a1); a2 = fmaf(k4, c1, a2); \
      a3 = fmaf(k4, c2, a3); a4 = fmaf(k4, c3, a4); n4 = sptr[(S)+14]; }

// last full segment (S=40): only s[50] (c0) is needed beyond — drop dead loads
#define SEGAL(S) \
    { float k0 = wrow[(S)], k1 = wrow[(S)+1], k2 = wrow[(S)+2], \
            k3 = wrow[(S)+3], k4 = wrow[(S)+4]; \
      a0 = fmaf(k0, c0, a0); a1 = fmaf(k0, c1, a1); a2 = fmaf(k0, c2, a2); \
      a3 = fmaf(k0, c3, a3); a4 = fmaf(k0, c4, a4); c0 = sptr[(S)+10]; \
      a0 = fmaf(k1, c1, a0); a1 = fmaf(k1, c2, a1); a2 = fmaf(k1, c3, a2); \
      a3 = fmaf(k1, c4, a3); a4 = fmaf(k1, n0, a4); \
      a0 = fmaf(k2, c2, a0); a1 = fmaf(k2, c3, a1); a2 = fmaf(k2, c4, a2); \
      a3 = fmaf(k2, n0, a3); a4 = fmaf(k2, n1, a4); \
      a0 = fmaf(k3, c3, a0); a1 = fmaf(k3, c4, a1); a2 = fmaf(k3, n0, a2); \
      a3 = fmaf(k3, n1, a3); a4 = fmaf(k3, n2, a4); \
      a0 = fmaf(k4, c4, a0); a1 = fmaf(k4, n0, a1); a2 = fmaf(k4, n1, a2); \
      a3 = fmaf(k4, n2, a3); a4 = fmaf(k4, n3, a4); }

// ---------------- kernel: conv + channel max/argmax (+ output zero-fill) ----
// grid = 1024 (4 blocks/CU, fully resident); items 1024..1103 folded onto
// blocks 0..79. 512 threads = 8 waves; wave wq owns channels [8wq, 8wq+8).
__launch_bounds__(512, 8)
__global__ void k_conv(const float* __restrict__ in, const float* __restrict__ wkf,
                       const int* __restrict__ kstab, const float* __restrict__ bias,
                       float* __restrict__ m_out, int* __restrict__ a_out,
                       float4* __restrict__ out4) {
    __shared__ __align__(16) union {
        float sp[30][TPAD_];                                   // 24000 B
        struct { float m[8][64][5]; int a[8][64][5]; } red;    // 20480 B
    } u;

    int bid = blockIdx.x;
    int tid  = threadIdx.x;
    int lane = tid & 63;
    int dy   = lane >> 5;                 // 0/1
    int tg   = lane & 31;                 // t-group
    int t0   = (tg < 29) ? tg * 5 : 140;  // clamp garbage lanes in-bounds
    int wq    = __builtin_amdgcn_readfirstlane(tid >> 6);
    int obase = wq * 8;

    // zero the spike output once (fire-and-forget, hidden under compute)
    {
        float4 z = make_float4(0.f, 0.f, 0.f, 0.f);
        for (int i2 = bid * 512 + tid; i2 < NOUT4; i2 += GRID_ * 512) out4[i2] = z;
    }

#pragma unroll 1
    for (int item = bid; item < NITEM; item += GRID_) {
        int b  = item / (XO_ * 12);
        int r  = item % (XO_ * 12);
        int x  = r / 12;
        int y0 = (r % 12) * 2;
        int y  = y0 + dy;
        bool valid = (y < XO_) && (tg < 29);

        // zero pad (float4) then fill rows. row = (i*3+kx)*5 + c, col = 2*y0+c
        for (int q = tid; q < 30 * TPAD_ / 4; q += 512)
            ((float4*)u.sp)[q] = make_float4(0.f, 0.f, 0.f, 0.f);
        __syncthreads();
        for (int q = tid; q < 30 * 24; q += 512) {
            int row = q / 24, f4 = q % 24;
            int c = row % 5, rr = row / 5;
            int kx = rr % 3, i = rr / 3;
            int col = 2 * y0 + c;
            if (col < W_) {
                const float4* src = (const float4*)(in +
                    ((((size_t)b * CI_ + i) * H_ + (2 * x + kx)) * W_ + col) * T_);
                *(float4*)(&u.sp[row][48 + f4 * 4]) = src[f4];
            }
        }
        __syncthreads();

        float mbest[5];
        int   abest[5];
#pragma unroll
        for (int j = 0; j < 5; ++j) { mbest[j] = -1e30f; abest[j] = 0; }

        const float* sbase = &u.sp[0][0] + 2 * dy * TPAD_ + t0;

#pragma unroll 1
        for (int oi = 0; oi < 8; ++oi) {
            int o = obase + oi;
            const int* ksrow = kstab + o * NTAP_;
            const float* wrow = wkf + o * (NTAP_ * 48);       // advanced per tap
            const float* sptr = sbase;                        // advanced per tap
            int ky3 = 0;
            float a0 = 0.f, a1 = 0.f, a2 = 0.f, a3 = 0.f, a4 = 0.f;
            int ks_next = ksrow[0];
#pragma unroll 1
            for (int tap = 0; tap < NTAP_; ++tap) {
                int ksv = __builtin_amdgcn_readfirstlane(ks_next);
                if (tap + 1 < NTAP_) ks_next = ksrow[tap + 1];  // prefetch next
                int ks = ksv & 63;
                if (ks < 48) {
                    int par = ksv >> 8;
                    const float* sk = sptr + ks;
                    float c0, c1, c2, c3, c4, n0, n1, n2, n3, n4;
                    if (par == 0) {      // entry segment is a SEGA position
                        c0 = sk[0]; c1 = sk[1]; c2 = sk[2]; c3 = sk[3]; c4 = sk[4];
                        n0 = sk[5]; n1 = sk[6]; n2 = sk[7]; n3 = sk[8]; n4 = sk[9];
                    } else {             // entry segment is a SEGB position
                        n0 = sk[0]; n1 = sk[1]; n2 = sk[2]; n3 = sk[3]; n4 = sk[4];
                        c0 = sk[5]; c1 = sk[6]; c2 = sk[7]; c3 = sk[8]; c4 = sk[9];
                    }
                    if (ks <= 0)  SEGA(0)
                    if (ks <= 5)  SEGB(5)
                    if (ks <= 10) SEGA(10)
                    if (ks <= 15) SEGB(15)
                    if (ks <= 20) SEGA(20)
                    if (ks <= 25) SEGB(25)
                    if (ks <= 30) SEGA(30)
                    if (ks <= 35) SEGB(35)
                    if (ks <= 40) SEGAL(40)
                    {   // tail kt = 45,46 (K[47]==0): n = s[45..49], c0 = s[50]
                        float k45 = wrow[45], k46 = wrow[46];
                        a0 = fmaf(k45, n0, a0); a1 = fmaf(k45, n1, a1);
                        a2 = fmaf(k45, n2, a2); a3 = fmaf(k45, n3, a3);
                        a4 = fmaf(k45, n4, a4);
                        a0 = fmaf(k46, n1, a0); a1 = fmaf(k46, n2, a1);
                        a2 = fmaf(k46, n3, a2); a3 = fmaf(k46, n4, a3);
                        a4 = fmaf(k46, c0, a4);
                    }
                }
                // advance pointers: row += 1 (ky++), or += 3 on ky wrap
                wrow += 48;
                if (++ky3 == 3) { ky3 = 0; sptr += 3 * TPAD_; }
                else            { sptr += TPAD_; }
            }
            // incremental max/argmax (strict >, o ascending => smallest o wins ties)
            float bo = bias[o];
            float p0 = a0 + bo, p1 = a1 + bo, p2 = a2 + bo, p3 = a3 + bo, p4 = a4 + bo;
            if (p0 > mbest[0]) { mbest[0] = p0; abest[0] = o; }
            if (p1 > mbest[1]) { mbest[1] = p1; abest[1] = o; }
            if (p2 > mbest[2]) { mbest[2] = p2; abest[2] = o; }
            if (p3 > mbest[3]) { mbest[3] = p3; abest[3] = o; }
            if (p4 > mbest[4]) { mbest[4] = p4; abest[4] = o; }
        }

        __syncthreads();   // done reading u.sp — safe to overwrite with u.red
#pragma unroll
        for (int j = 0; j < 5; ++j) {
            u.red.m[wq][lane][j] = mbest[j];
            u.red.a[wq][lane][j] = abest[j];
        }
        __syncthreads();
        if (wq == 0 && valid) {
            int site = x * XO_ + y;
#pragma unroll
            for (int j = 0; j < 5; ++j) {
                float mv = u.red.m[0][lane][j];
                int   av = u.red.a[0][lane][j];
#pragma unroll
                for (int w = 1; w < 8; ++w) {
                    float m2 = u.red.m[w][lane][j];
                    if (m2 > mv) { mv = m2; av = u.red.a[w][lane][j]; }
                }
                size_t off = ((size_t)b * TP_ + (t0 + j)) * NSITE + site;
                m_out[off] = mv;
                a_out[off] = av;
            }
        }
        __syncthreads();   // protect union reuse across fold iterations
    }
}

// ---------------- kernel: sequential WTA ----------------
// one block per batch, 576 threads (site = tid). coalesced [b][t][site] loads,
// next-t prefetch, 1 barrier/step via double-buffered counts.
__launch_bounds__(576)
__global__ void k_wta(const float* __restrict__ m_in, const int* __restrict__ a_in,
                      float* __restrict__ out) {
    int b = blockIdx.x;
    int tid = threadIdx.x;
    int lane = tid & 63;
    int wid = tid >> 6;                 // 9 waves
    __shared__ int cnts[2][9];

    bool site = (tid < NSITE);
    const float* mb = m_in + (size_t)b * TP_ * NSITE;
    const int*   ab = a_in + (size_t)b * TP_ * NSITE;
    int dep = 0;
    float mv = site ? mb[tid] : 0.f;
    int   av = site ? ab[tid] : 0;

    for (int t = 0; t < TP_; ++t) {
        unsigned long long ball = __ballot(dep != 0);
        if (lane == 0) cnts[t & 1][wid] = __popcll(ball);
        // prefetch next row while the barrier settles
        float mv2 = 0.f; int av2 = 0;
        if (site && t + 1 < TP_) {
            mv2 = mb[(t + 1) * NSITE + tid];
            av2 = ab[(t + 1) * NSITE + tid];
        }
        __syncthreads();
        int tot = 0;
#pragma unroll
        for (int w = 0; w < 9; ++w) tot += cnts[t & 1][w];
        if (site) {
            if ((tot < WCAP_) && (dep == 0) && (mv > THETA_)) {
                out[(((size_t)b * CO_ + av) * NSITE + tid) * TP_ + t] = 1.0f;
                dep = FODEP_ - 1;
            } else {
                dep = dep ? dep - 1 : 0;
            }
        }
        mv = mv2; av = av2;
    }
}

// ---------------- launcher ----------------
extern "C" void kernel_launch(void* const* d_in, const int* in_sizes, int n_in,
                              void* d_out, int out_size, void* d_ws, size_t ws_size,
                              hipStream_t stream) {
    const float* in     = (const float*)d_in[0];
    const float* weight = (const float*)d_in[1];
    const float* bias   = (const float*)d_in[2];
    float* out = (float*)d_out;

    float* wkf   = (float*)d_ws + WS_WKF;
    int*   kstab = (int*)((float*)d_ws + WS_KS);
    float* m     = (float*)d_ws + WS_M;
    int*   a     = (int*)((float*)d_ws + WS_A);

    k_wk<<<(CO_ * NTAP_ + 255) / 256, 256, 0, stream>>>(weight, wkf, kstab);
    k_conv<<<GRID_, 512, 0, stream>>>(in, wkf, kstab, bias, m, a, (float4*)out);
    k_wta<<<B_, 576, 0, stream>>>(m, a, out);
}

// Round 10
// 345.131 us; speedup vs baseline: 1.1836x; 1.0683x over previous
//
#include <hip/hip_runtime.h>

// ---------------- problem constants ----------------
#define B_    4
#define CI_   2
#define H_    48
#define W_    48
#define T_    96
#define CO_   64
#define XO_   23
#define NSITE 529         // 23*23
#define TP_   145         // output time steps (29*5)
#define TPAD_ 200         // padded LDS time window per row (max read idx 194)
#define NTAP_ 18          // CI*3*3
#define NITEM (B_ * XO_ * 12)   // 1104 site-chunks
#define GRID_ 1024
#define THETA_ 5.4f
#define FODEP_ 48
#define WCAP_  265        // ceil(0.5*529)
#define NOUT4 (19636480 / 4)

// ws layout (floats)
#define WS_WKF 0                      // [64][18][48] = 55296 floats
#define WS_KS  55296                  // [64][18] ints
#define WS_M   (55296 + 1152)         // [4][145][529] floats
#define WS_A   (WS_M + 306820)        // [4][145][529] ints

// ---------------- kernel: temporal kernel synthesis + start-index table ----
// kstab packs: ks (low 6 bits) | parity=(ks/5)&1 << 8  (48 = empty kernel)
__global__ void k_wk(const float* __restrict__ weight, float* __restrict__ wkf,
                     int* __restrict__ kstab) {
    int idx = blockIdx.x * 256 + threadIdx.x;       // (o, tap)
    if (idx >= CO_ * NTAP_) return;
    int o = idx / NTAP_, tap = idx % NTAP_;
    int i = tap / 9, kx = (tap % 9) / 3, ky = tap % 3;
    float w = weight[((o * CI_ + i) * 3 + kx) * 3 + ky];
    int ktlo = 48;
    for (int kt = 0; kt < 48; ++kt) {
        float j = (float)(47 - kt);
        float v = fmaxf(0.0f, fminf(j * (1.0f / 16.0f), 1.5f * w - j * (1.0f / 32.0f)));
        wkf[idx * 48 + kt] = v;
        if (v > 0.0f && ktlo == 48) ktlo = kt;
    }
    if (ktlo >= 48) { kstab[idx] = 48; return; }
    int ks = ktlo - ktlo % 5;
    kstab[idx] = ks | (((ks / 5) & 1) << 8);
}

// ---- two-bank ping-pong FIR segments (zero movs, distance-2-segment prefetch)
// SEGA(S): cur bank = c (c_j == s[t0+S+j]), next = n (n_j == s[t0+S+5+j]).
// each phase reloads its dead cur-register with s[t0+S+10+j].
// FMA order per accumulator: ascending kt — bit-identical across rounds.
#define SEGA(S) \
    { float k0 = wrow[(S)], k1 = wrow[(S)+1], k2 = wrow[(S)+2], \
            k3 = wrow[(S)+3], k4 = wrow[(S)+4]; \
      a0 = fmaf(k0, c0, a0); a1 = fmaf(k0, c1, a1); a2 = fmaf(k0, c2, a2); \
      a3 = fmaf(k0, c3, a3); a4 = fmaf(k0, c4, a4); c0 = sptr[(S)+10]; \
      a0 = fmaf(k1, c1, a0); a1 = fmaf(k1, c2, a1); a2 = fmaf(k1, c3, a2); \
      a3 = fmaf(k1, c4, a3); a4 = fmaf(k1, n0, a4); c1 = sptr[(S)+11]; \
      a0 = fmaf(k2, c2, a0); a1 = fmaf(k2, c3, a1); a2 = fmaf(k2, c4, a2); \
      a3 = fmaf(k2, n0, a3); a4 = fmaf(k2, n1, a4); c2 = sptr[(S)+12]; \
      a0 = fmaf(k3, c3, a0); a1 = fmaf(k3, c4, a1); a2 = fmaf(k3, n0, a2); \
      a3 = fmaf(k3, n1, a3); a4 = fmaf(k3, n2, a4); c3 = sptr[(S)+13]; \
      a0 = fmaf(k4, c4, a0); a1 = fmaf(k4, n0, a1); a2 = fmaf(k4, n1, a2); \
      a3 = fmaf(k4, n2, a3); a4 = fmaf(k4, n3, a4); c4 = sptr[(S)+14]; }

#define SEGB(S) \
    { float k0 = wrow[(S)], k1 = wrow[(S)+1], k2 = wrow[(S)+2], \
            k3 = wrow[(S)+3], k4 = wrow[(S)+4]; \
      a0 = fmaf(k0, n0, a0); a1 = fmaf(k0, n1, a1); a2 = fmaf(k0, n2, a2); \
      a3 = fmaf(k0, n3, a3); a4 = fmaf(k0, n4, a4); n0 = sptr[(S)+10]; \
      a0 = fmaf(k1, n1, a0); a1 = fmaf(k1, n2, a1); a2 = fmaf(k1, n3, a2); \
      a3 = fmaf(k1, n4, a3); a4 = fmaf(k1, c0, a4); n1 = sptr[(S)+11]; \
      a0 = fmaf(k2, n2, a0); a1 = fmaf(k2, n3, a1); a2 = fmaf(k2, n4, a2); \
      a3 = fmaf(k2, c0, a3); a4 = fmaf(k2, c1, a4); n2 = sptr[(S)+12]; \
      a0 = fmaf(k3, n3, a0); a1 = fmaf(k3, n4, a1); a2 = fmaf(k3, c0, a2); \
      a3 = fmaf(k3, c1, a3); a4 = fmaf(k3, c2, a4); n3 = sptr[(S)+13]; \
      a0 = fmaf(k4, n4, a0); a1 = fmaf(k4, c0, a1); a2 = fmaf(k4, c1, a2); \
      a3 = fmaf(k4, c2, a3); a4 = fmaf(k4, c3, a4); n4 = sptr[(S)+14]; }

// last full segment (S=40): only s[50] (c0) is needed beyond — drop dead loads
#define SEGAL(S) \
    { float k0 = wrow[(S)], k1 = wrow[(S)+1], k2 = wrow[(S)+2], \
            k3 = wrow[(S)+3], k4 = wrow[(S)+4]; \
      a0 = fmaf(k0, c0, a0); a1 = fmaf(k0, c1, a1); a2 = fmaf(k0, c2, a2); \
      a3 = fmaf(k0, c3, a3); a4 = fmaf(k0, c4, a4); c0 = sptr[(S)+10]; \
      a0 = fmaf(k1, c1, a0); a1 = fmaf(k1, c2, a1); a2 = fmaf(k1, c3, a2); \
      a3 = fmaf(k1, c4, a3); a4 = fmaf(k1, n0, a4); \
      a0 = fmaf(k2, c2, a0); a1 = fmaf(k2, c3, a1); a2 = fmaf(k2, c4, a2); \
      a3 = fmaf(k2, n0, a3); a4 = fmaf(k2, n1, a4); \
      a0 = fmaf(k3, c3, a0); a1 = fmaf(k3, c4, a1); a2 = fmaf(k3, n0, a2); \
      a3 = fmaf(k3, n1, a3); a4 = fmaf(k3, n2, a4); \
      a0 = fmaf(k4, c4, a0); a1 = fmaf(k4, n0, a1); a2 = fmaf(k4, n1, a2); \
      a3 = fmaf(k4, n2, a3); a4 = fmaf(k4, n3, a4); }

// ---------------- kernel: conv + channel max/argmax (+ output zero-fill) ----
// grid = 1024 (4 blocks/CU, fully resident); items 1024..1103 folded onto
// blocks 0..79. 512 threads = 8 waves; wave wq owns channels [8wq, 8wq+8).
__launch_bounds__(512, 8)
__global__ void k_conv(const float* __restrict__ in, const float* __restrict__ wkf,
                       const int* __restrict__ kstab, const float* __restrict__ bias,
                       float* __restrict__ m_out, int* __restrict__ a_out,
                       float4* __restrict__ out4) {
    __shared__ __align__(16) union {
        float sp[30][TPAD_];                                   // 24000 B
        struct { float m[8][64][5]; int a[8][64][5]; } red;    // 20480 B
    } u;

    int bid = blockIdx.x;
    int tid  = threadIdx.x;
    int lane = tid & 63;
    int dy   = lane >> 5;                 // 0/1
    int tg   = lane & 31;                 // t-group
    int t0   = (tg < 29) ? tg * 5 : 140;  // clamp garbage lanes in-bounds
    int wq    = __builtin_amdgcn_readfirstlane(tid >> 6);
    int obase = wq * 8;

    // zero the spike output once (fire-and-forget, hidden under compute)
    {
        float4 z = make_float4(0.f, 0.f, 0.f, 0.f);
        for (int i2 = bid * 512 + tid; i2 < NOUT4; i2 += GRID_ * 512) out4[i2] = z;
    }

#pragma unroll 1
    for (int item = bid; item < NITEM; item += GRID_) {
        int b  = item / (XO_ * 12);
        int r  = item % (XO_ * 12);
        int x  = r / 12;
        int y0 = (r % 12) * 2;
        int y  = y0 + dy;
        bool valid = (y < XO_) && (tg < 29);

        // zero pad (float4) then fill rows. row = (i*3+kx)*5 + c, col = 2*y0+c
        for (int q = tid; q < 30 * TPAD_ / 4; q += 512)
            ((float4*)u.sp)[q] = make_float4(0.f, 0.f, 0.f, 0.f);
        __syncthreads();
        for (int q = tid; q < 30 * 24; q += 512) {
            int row = q / 24, f4 = q % 24;
            int c = row % 5, rr = row / 5;
            int kx = rr % 3, i = rr / 3;
            int col = 2 * y0 + c;
            if (col < W_) {
                const float4* src = (const float4*)(in +
                    ((((size_t)b * CI_ + i) * H_ + (2 * x + kx)) * W_ + col) * T_);
                *(float4*)(&u.sp[row][48 + f4 * 4]) = src[f4];
            }
        }
        __syncthreads();

        float mbest[5];
        int   abest[5];
#pragma unroll
        for (int j = 0; j < 5; ++j) { mbest[j] = -1e30f; abest[j] = 0; }

        const float* sbase = &u.sp[0][0] + 2 * dy * TPAD_ + t0;

#pragma unroll 1
        for (int oi = 0; oi < 8; ++oi) {
            int o = obase + oi;
            const int* ksrow = kstab + o * NTAP_;
            const float* wrow = wkf + o * (NTAP_ * 48);       // advanced per tap
            const float* sptr = sbase;                        // advanced per tap
            int ky3 = 0;
            float a0 = 0.f, a1 = 0.f, a2 = 0.f, a3 = 0.f, a4 = 0.f;
            int ks_next = ksrow[0];
#pragma unroll 1
            for (int tap = 0; tap < NTAP_; ++tap) {
                int ksv = __builtin_amdgcn_readfirstlane(ks_next);
                if (tap + 1 < NTAP_) ks_next = ksrow[tap + 1];  // prefetch next
                int ks = ksv & 63;
                if (ks < 48) {
                    int par = ksv >> 8;
                    const float* sk  = sptr + ks;
                    // uniform 2-pointer bank select (same values as the old
                    // 10-way cndmask init; c/n roles per entry-segment parity)
                    const float* skc = par ? (sk + 5) : sk;
                    const float* skn = par ? sk : (sk + 5);
                    float c0 = skc[0], c1 = skc[1], c2 = skc[2], c3 = skc[3], c4 = skc[4];
                    float n0 = skn[0], n1 = skn[1], n2 = skn[2], n3 = skn[3], n4 = skn[4];
                    if (ks <= 0)  SEGA(0)
                    if (ks <= 5)  SEGB(5)
                    if (ks <= 10) SEGA(10)
                    if (ks <= 15) SEGB(15)
                    if (ks <= 20) SEGA(20)
                    if (ks <= 25) SEGB(25)
                    if (ks <= 30) SEGA(30)
                    if (ks <= 35) SEGB(35)
                    if (ks <= 40) SEGAL(40)
                    {   // tail kt = 45,46 (K[47]==0): n = s[45..49], c0 = s[50]
                        float k45 = wrow[45], k46 = wrow[46];
                        a0 = fmaf(k45, n0, a0); a1 = fmaf(k45, n1, a1);
                        a2 = fmaf(k45, n2, a2); a3 = fmaf(k45, n3, a3);
                        a4 = fmaf(k45, n4, a4);
                        a0 = fmaf(k46, n1, a0); a1 = fmaf(k46, n2, a1);
                        a2 = fmaf(k46, n3, a2); a3 = fmaf(k46, n4, a3);
                        a4 = fmaf(k46, c0, a4);
                    }
                }
                // advance pointers: row += 1 (ky++), or += 3 on ky wrap
                wrow += 48;
                if (++ky3 == 3) { ky3 = 0; sptr += 3 * TPAD_; }
                else            { sptr += TPAD_; }
            }
            // incremental max/argmax (strict >, o ascending => smallest o wins ties)
            float bo = bias[o];
            float p0 = a0 + bo, p1 = a1 + bo, p2 = a2 + bo, p3 = a3 + bo, p4 = a4 + bo;
            if (p0 > mbest[0]) { mbest[0] = p0; abest[0] = o; }
            if (p1 > mbest[1]) { mbest[1] = p1; abest[1] = o; }
            if (p2 > mbest[2]) { mbest[2] = p2; abest[2] = o; }
            if (p3 > mbest[3]) { mbest[3] = p3; abest[3] = o; }
            if (p4 > mbest[4]) { mbest[4] = p4; abest[4] = o; }
        }

        __syncthreads();   // done reading u.sp — safe to overwrite with u.red
#pragma unroll
        for (int j = 0; j < 5; ++j) {
            u.red.m[wq][lane][j] = mbest[j];
            u.red.a[wq][lane][j] = abest[j];
        }
        __syncthreads();
        if (wq == 0 && valid) {
            int site = x * XO_ + y;
#pragma unroll
            for (int j = 0; j < 5; ++j) {
                float mv = u.red.m[0][lane][j];
                int   av = u.red.a[0][lane][j];
#pragma unroll
                for (int w = 1; w < 8; ++w) {
                    float m2 = u.red.m[w][lane][j];
                    if (m2 > mv) { mv = m2; av = u.red.a[w][lane][j]; }
                }
                size_t off = ((size_t)b * TP_ + (t0 + j)) * NSITE + site;
                m_out[off] = mv;
                a_out[off] = av;
            }
        }
        __syncthreads();   // protect union reuse across fold iterations
    }
}

// ---------------- kernel: sequential WTA, 4-deep prefetch ring ----------------
// one block per batch, 576 threads (site = tid). coalesced [b][t][site] loads.
// ring slots hold t..t+3; each step issues the t+4 load BEFORE its barrier, so
// every load has ~4 barrier-periods (~1000 cyc) to complete — L2/L3 latency
// fully hidden. Static slot names (no runtime-indexed arrays -> no scratch).
#define WSTEP(MC, AC, TT)                                                      \
    {                                                                          \
        int t_ = (TT);                                                         \
        unsigned long long ball = __ballot(dep != 0);                          \
        if (lane == 0) cnts[t_ & 1][wid] = __popcll(ball);                     \
        float cm = MC; int ca = AC;                                            \
        if (site && t_ + 4 < TP_) {                                            \
            MC = mb[(size_t)(t_ + 4) * NSITE + tid];                           \
            AC = ab[(size_t)(t_ + 4) * NSITE + tid];                           \
        }                                                                      \
        __syncthreads();                                                       \
        int tot = 0;                                                           \
        _Pragma("unroll") for (int w = 0; w < 9; ++w) tot += cnts[t_ & 1][w];  \
        if (site) {                                                            \
            if ((tot < WCAP_) && (dep == 0) && (cm > THETA_)) {                \
                out[(((size_t)b * CO_ + ca) * NSITE + tid) * TP_ + t_] = 1.0f; \
                dep = FODEP_ - 1;                                              \
            } else {                                                           \
                dep = dep ? dep - 1 : 0;                                       \
            }                                                                  \
        }                                                                      \
    }

__launch_bounds__(576)
__global__ void k_wta(const float* __restrict__ m_in, const int* __restrict__ a_in,
                      float* __restrict__ out) {
    int b = blockIdx.x;
    int tid = threadIdx.x;
    int lane = tid & 63;
    int wid = tid >> 6;                 // 9 waves
    __shared__ int cnts[2][9];

    bool site = (tid < NSITE);
    const float* mb = m_in + (size_t)b * TP_ * NSITE;
    const int*   ab = a_in + (size_t)b * TP_ * NSITE;
    int dep = 0;

    float m0 = 0.f, m1 = 0.f, m2 = 0.f, m3 = 0.f;
    int   a0 = 0,   a1 = 0,   a2 = 0,   a3 = 0;
    if (site) {
        m0 = mb[0 * NSITE + tid]; a0 = ab[0 * NSITE + tid];
        m1 = mb[1 * NSITE + tid]; a1 = ab[1 * NSITE + tid];
        m2 = mb[2 * NSITE + tid]; a2 = ab[2 * NSITE + tid];
        m3 = mb[3 * NSITE + tid]; a3 = ab[3 * NSITE + tid];
    }

    for (int t = 0; t < TP_; t += 4) {
        WSTEP(m0, a0, t);
        if (t + 1 < TP_) WSTEP(m1, a1, t + 1);
        if (t + 2 < TP_) WSTEP(m2, a2, t + 2);
        if (t + 3 < TP_) WSTEP(m3, a3, t + 3);
    }
}

// ---------------- launcher ----------------
extern "C" void kernel_launch(void* const* d_in, const int* in_sizes, int n_in,
                              void* d_out, int out_size, void* d_ws, size_t ws_size,
                              hipStream_t stream) {
    const float* in     = (const float*)d_in[0];
    const float* weight = (const float*)d_in[1];
    const float* bias   = (const float*)d_in[2];
    float* out = (float*)d_out;

    float* wkf   = (float*)d_ws + WS_WKF;
    int*   kstab = (int*)((float*)d_ws + WS_KS);
    float* m     = (float*)d_ws + WS_M;
    int*   a     = (int*)((float*)d_ws + WS_A);

    k_wk<<<(CO_ * NTAP_ + 255) / 256, 256, 0, stream>>>(weight, wkf, kstab);
    k_conv<<<GRID_, 512, 0, stream>>>(in, wkf, kstab, bias, m, a, (float4*)out);
    k_wta<<<B_, 576, 0, stream>>>(m, a, out);
}

// Round 11
// 343.928 us; speedup vs baseline: 1.1878x; 1.0035x over previous
//
#include <hip/hip_runtime.h>

// ---------------- problem constants ----------------
#define B_    4
#define CI_   2
#define H_    48
#define W_    48
#define T_    96
#define CO_   64
#define XO_   23
#define NSITE 529         // 23*23
#define TP_   145         // output time steps (29*5)
#define TPAD_ 200         // padded LDS time window per row (max read idx 194)
#define NTAP_ 18          // CI*3*3
#define NITEM (B_ * XO_ * 12)   // 1104 site-chunks
#define GRID_ 1024
#define THETA_ 5.4f
#define FODEP_ 48
#define WCAP_  265        // ceil(0.5*529)
#define NOUT4 (19636480 / 4)

// ws layout (floats)
#define WS_WKF 0                      // [64][18][48] = 55296 floats
#define WS_KS  55296                  // [64][18] ints
#define WS_M   (55296 + 1152)         // [4][145][529] floats
#define WS_A   (WS_M + 306820)        // [4][145][529] ints

// ---------------- kernel: temporal kernel synthesis + start-index table ----
// kstab packs: ks (low 6 bits) | parity=(ks/5)&1 << 8  (48 = empty kernel)
__global__ void k_wk(const float* __restrict__ weight, float* __restrict__ wkf,
                     int* __restrict__ kstab) {
    int idx = blockIdx.x * 256 + threadIdx.x;       // (o, tap)
    if (idx >= CO_ * NTAP_) return;
    int o = idx / NTAP_, tap = idx % NTAP_;
    int i = tap / 9, kx = (tap % 9) / 3, ky = tap % 3;
    float w = weight[((o * CI_ + i) * 3 + kx) * 3 + ky];
    int ktlo = 48;
    for (int kt = 0; kt < 48; ++kt) {
        float j = (float)(47 - kt);
        float v = fmaxf(0.0f, fminf(j * (1.0f / 16.0f), 1.5f * w - j * (1.0f / 32.0f)));
        wkf[idx * 48 + kt] = v;
        if (v > 0.0f && ktlo == 48) ktlo = kt;
    }
    if (ktlo >= 48) { kstab[idx] = 48; return; }
    int ks = ktlo - ktlo % 5;
    kstab[idx] = ks | (((ks / 5) & 1) << 8);
}

// 32-bit-index LDS access: compiles to ds_read_b32 vaddr, offset:imm
#define LDSW(I) u.spf[sidx + (I)]

// ---- two-bank ping-pong FIR segments (zero movs, distance-2-segment prefetch)
// SEGA(S): cur bank = c (c_j == s[S+j]), next = n (n_j == s[S+5+j]).
// each phase reloads its dead cur-register with s[S+10+j].
// FMA order per accumulator: ascending kt — bit-identical across rounds.
#define SEGA(S) \
    { float k0 = wrow[(S)], k1 = wrow[(S)+1], k2 = wrow[(S)+2], \
            k3 = wrow[(S)+3], k4 = wrow[(S)+4]; \
      a0 = fmaf(k0, c0, a0); a1 = fmaf(k0, c1, a1); a2 = fmaf(k0, c2, a2); \
      a3 = fmaf(k0, c3, a3); a4 = fmaf(k0, c4, a4); c0 = LDSW((S)+10); \
      a0 = fmaf(k1, c1, a0); a1 = fmaf(k1, c2, a1); a2 = fmaf(k1, c3, a2); \
      a3 = fmaf(k1, c4, a3); a4 = fmaf(k1, n0, a4); c1 = LDSW((S)+11); \
      a0 = fmaf(k2, c2, a0); a1 = fmaf(k2, c3, a1); a2 = fmaf(k2, c4, a2); \
      a3 = fmaf(k2, n0, a3); a4 = fmaf(k2, n1, a4); c2 = LDSW((S)+12); \
      a0 = fmaf(k3, c3, a0); a1 = fmaf(k3, c4, a1); a2 = fmaf(k3, n0, a2); \
      a3 = fmaf(k3, n1, a3); a4 = fmaf(k3, n2, a4); c3 = LDSW((S)+13); \
      a0 = fmaf(k4, c4, a0); a1 = fmaf(k4, n0, a1); a2 = fmaf(k4, n1, a2); \
      a3 = fmaf(k4, n2, a3); a4 = fmaf(k4, n3, a4); c4 = LDSW((S)+14); }

#define SEGB(S) \
    { float k0 = wrow[(S)], k1 = wrow[(S)+1], k2 = wrow[(S)+2], \
            k3 = wrow[(S)+3], k4 = wrow[(S)+4]; \
      a0 = fmaf(k0, n0, a0); a1 = fmaf(k0, n1, a1); a2 = fmaf(k0, n2, a2); \
      a3 = fmaf(k0, n3, a3); a4 = fmaf(k0, n4, a4); n0 = LDSW((S)+10); \
      a0 = fmaf(k1, n1, a0); a1 = fmaf(k1, n2, a1); a2 = fmaf(k1, n3, a2); \
      a3 = fmaf(k1, n4, a3); a4 = fmaf(k1, c0, a4); n1 = LDSW((S)+11); \
      a0 = fmaf(k2, n2, a0); a1 = fmaf(k2, n3, a1); a2 = fmaf(k2, n4, a2); \
      a3 = fmaf(k2, c0, a3); a4 = fmaf(k2, c1, a4); n2 = LDSW((S)+12); \
      a0 = fmaf(k3, n3, a0); a1 = fmaf(k3, n4, a1); a2 = fmaf(k3, c0, a2); \
      a3 = fmaf(k3, c1, a3); a4 = fmaf(k3, c2, a4); n3 = LDSW((S)+13); \
      a0 = fmaf(k4, n4, a0); a1 = fmaf(k4, c0, a1); a2 = fmaf(k4, c1, a2); \
      a3 = fmaf(k4, c2, a3); a4 = fmaf(k4, c3, a4); n4 = LDSW((S)+14); }

// last full segment (S=40): only s[50] (c0) is needed beyond — drop dead loads
#define SEGAL(S) \
    { float k0 = wrow[(S)], k1 = wrow[(S)+1], k2 = wrow[(S)+2], \
            k3 = wrow[(S)+3], k4 = wrow[(S)+4]; \
      a0 = fmaf(k0, c0, a0); a1 = fmaf(k0, c1, a1); a2 = fmaf(k0, c2, a2); \
      a3 = fmaf(k0, c3, a3); a4 = fmaf(k0, c4, a4); c0 = LDSW((S)+10); \
      a0 = fmaf(k1, c1, a0); a1 = fmaf(k1, c2, a1); a2 = fmaf(k1, c3, a2); \
      a3 = fmaf(k1, c4, a3); a4 = fmaf(k1, n0, a4); \
      a0 = fmaf(k2, c2, a0); a1 = fmaf(k2, c3, a1); a2 = fmaf(k2, c4, a2); \
      a3 = fmaf(k2, n0, a3); a4 = fmaf(k2, n1, a4); \
      a0 = fmaf(k3, c3, a0); a1 = fmaf(k3, c4, a1); a2 = fmaf(k3, n0, a2); \
      a3 = fmaf(k3, n1, a3); a4 = fmaf(k3, n2, a4); \
      a0 = fmaf(k4, c4, a0); a1 = fmaf(k4, n0, a1); a2 = fmaf(k4, n1, a2); \
      a3 = fmaf(k4, n2, a3); a4 = fmaf(k4, n3, a4); }

// ---------------- kernel: conv + channel max/argmax (+ output zero-fill) ----
// grid = 1024 (4 blocks/CU, fully resident); items 1024..1103 folded onto
// blocks 0..79. 512 threads = 8 waves; wave wq owns channels [8wq, 8wq+8).
__launch_bounds__(512, 8)
__global__ void k_conv(const float* __restrict__ in, const float* __restrict__ wkf,
                       const int* __restrict__ kstab, const float* __restrict__ bias,
                       float* __restrict__ m_out, int* __restrict__ a_out,
                       float4* __restrict__ out4) {
    __shared__ __align__(16) union {
        float spf[30 * TPAD_];                                 // 24000 B
        struct { float m[8][64][5]; int a[8][64][5]; } red;    // 20480 B
    } u;

    int bid = blockIdx.x;
    int tid  = threadIdx.x;
    int lane = tid & 63;
    int dy   = lane >> 5;                 // 0/1
    int tg   = lane & 31;                 // t-group
    int t0   = (tg < 29) ? tg * 5 : 140;  // clamp garbage lanes in-bounds
    int wq    = __builtin_amdgcn_readfirstlane(tid >> 6);
    int obase = wq * 8;

    // zero the spike output once (fire-and-forget, hidden under compute)
    {
        float4 z = make_float4(0.f, 0.f, 0.f, 0.f);
        for (int i2 = bid * 512 + tid; i2 < NOUT4; i2 += GRID_ * 512) out4[i2] = z;
    }

#pragma unroll 1
    for (int item = bid; item < NITEM; item += GRID_) {
        int b  = item / (XO_ * 12);
        int r  = item % (XO_ * 12);
        int x  = r / 12;
        int y0 = (r % 12) * 2;
        int y  = y0 + dy;
        bool valid = (y < XO_) && (tg < 29);

        // zero pad (float4) then fill rows. row = (i*3+kx)*5 + c, col = 2*y0+c
        for (int q = tid; q < 30 * TPAD_ / 4; q += 512)
            ((float4*)u.spf)[q] = make_float4(0.f, 0.f, 0.f, 0.f);
        __syncthreads();
        for (int q = tid; q < 30 * 24; q += 512) {
            int row = q / 24, f4 = q % 24;
            int c = row % 5, rr = row / 5;
            int kx = rr % 3, i = rr / 3;
            int col = 2 * y0 + c;
            if (col < W_) {
                const float4* src = (const float4*)(in +
                    ((((size_t)b * CI_ + i) * H_ + (2 * x + kx)) * W_ + col) * T_);
                *(float4*)(&u.spf[row * TPAD_ + 48 + f4 * 4]) = src[f4];
            }
        }
        __syncthreads();

        float mbest[5];
        int   abest[5];
#pragma unroll
        for (int j = 0; j < 5; ++j) { mbest[j] = -1e30f; abest[j] = 0; }

        const int sb0 = 2 * dy * TPAD_ + t0;   // per-lane base index (row of tap0)

#pragma unroll 1
        for (int oi = 0; oi < 8; ++oi) {
            int o = obase + oi;
            const int* ksrow = kstab + o * NTAP_;
            const float* wrow = wkf + o * (NTAP_ * 48);       // advanced per tap
            int sidx = sb0;                                   // advanced per tap
            int ky3 = 0;
            float a0 = 0.f, a1 = 0.f, a2 = 0.f, a3 = 0.f, a4 = 0.f;
            int ks_next = ksrow[0];
#pragma unroll 1
            for (int tap = 0; tap < NTAP_; ++tap) {
                int ksv = __builtin_amdgcn_readfirstlane(ks_next);
                if (tap + 1 < NTAP_) ks_next = ksrow[tap + 1];  // prefetch next
                int ks = ksv & 63;
                if (ks < 48) {
                    int par = ksv >> 8;
                    // uniform bank-role select: c/n per entry-segment parity
                    int kb = sidx + ks;
                    int kc = par ? kb + 5 : kb;
                    int kn = par ? kb : kb + 5;
                    float c0 = u.spf[kc],     c1 = u.spf[kc + 1], c2 = u.spf[kc + 2],
                          c3 = u.spf[kc + 3], c4 = u.spf[kc + 4];
                    float n0 = u.spf[kn],     n1 = u.spf[kn + 1], n2 = u.spf[kn + 2],
                          n3 = u.spf[kn + 3], n4 = u.spf[kn + 4];
                    if (ks <= 0)  SEGA(0)
                    if (ks <= 5)  SEGB(5)
                    if (ks <= 10) SEGA(10)
                    if (ks <= 15) SEGB(15)
                    if (ks <= 20) SEGA(20)
                    if (ks <= 25) SEGB(25)
                    if (ks <= 30) SEGA(30)
                    if (ks <= 35) SEGB(35)
                    if (ks <= 40) SEGAL(40)
                    {   // tail kt = 45,46 (K[47]==0): n = s[45..49], c0 = s[50]
                        float k45 = wrow[45], k46 = wrow[46];
                        a0 = fmaf(k45, n0, a0); a1 = fmaf(k45, n1, a1);
                        a2 = fmaf(k45, n2, a2); a3 = fmaf(k45, n3, a3);
                        a4 = fmaf(k45, n4, a4);
                        a0 = fmaf(k46, n1, a0); a1 = fmaf(k46, n2, a1);
                        a2 = fmaf(k46, n3, a2); a3 = fmaf(k46, n4, a3);
                        a4 = fmaf(k46, c0, a4);
                    }
                }
                // advance: row += 1 (ky++), or += 3 on ky wrap
                wrow += 48;
                if (++ky3 == 3) { ky3 = 0; sidx += 3 * TPAD_; }
                else            { sidx += TPAD_; }
            }
            // incremental max/argmax (strict >, o ascending => smallest o wins ties)
            float bo = bias[o];
            float p0 = a0 + bo, p1 = a1 + bo, p2 = a2 + bo, p3 = a3 + bo, p4 = a4 + bo;
            if (p0 > mbest[0]) { mbest[0] = p0; abest[0] = o; }
            if (p1 > mbest[1]) { mbest[1] = p1; abest[1] = o; }
            if (p2 > mbest[2]) { mbest[2] = p2; abest[2] = o; }
            if (p3 > mbest[3]) { mbest[3] = p3; abest[3] = o; }
            if (p4 > mbest[4]) { mbest[4] = p4; abest[4] = o; }
        }

        __syncthreads();   // done reading u.spf — safe to overwrite with u.red
#pragma unroll
        for (int j = 0; j < 5; ++j) {
            u.red.m[wq][lane][j] = mbest[j];
            u.red.a[wq][lane][j] = abest[j];
        }
        __syncthreads();
        if (wq == 0 && valid) {
            int site = x * XO_ + y;
#pragma unroll
            for (int j = 0; j < 5; ++j) {
                float mv = u.red.m[0][lane][j];
                int   av = u.red.a[0][lane][j];
#pragma unroll
                for (int w = 1; w < 8; ++w) {
                    float m2 = u.red.m[w][lane][j];
                    if (m2 > mv) { mv = m2; av = u.red.a[w][lane][j]; }
                }
                size_t off = ((size_t)b * TP_ + (t0 + j)) * NSITE + site;
                m_out[off] = mv;
                a_out[off] = av;
            }
        }
        __syncthreads();   // protect union reuse across fold iterations
    }
}

// ---------------- kernel: sequential WTA, 4-deep ring + raw barrier ----------
// one block per batch, 576 threads (site = tid). coalesced [b][t][site] loads.
// KEY: raw s_barrier with lgkmcnt(0)-only wait — __syncthreads would drain
// vmcnt(0), killing the prefetch and serializing the out[] stores per step.
// LDS cnts writes are ordered by lgkmcnt(0)+barrier; global loads/stores stay
// in flight across the barrier (backend inserts vmcnt waits at use sites).
#define WBAR() do { \
    asm volatile("s_waitcnt lgkmcnt(0)" ::: "memory"); \
    __builtin_amdgcn_s_barrier(); \
    asm volatile("" ::: "memory"); \
} while (0)

#define WSTEP(MC, AC, TT)                                                      \
    {                                                                          \
        int t_ = (TT);                                                         \
        unsigned long long ball = __ballot(dep != 0);                          \
        if (lane == 0) cnts[t_ & 1][wid] = __popcll(ball);                     \
        float cm = MC; int ca = AC;                                            \
        if (site && t_ + 4 < TP_) {                                            \
            MC = mb[(size_t)(t_ + 4) * NSITE + tid];                           \
            AC = ab[(size_t)(t_ + 4) * NSITE + tid];                           \
        }                                                                      \
        WBAR();                                                                \
        int tot = 0;                                                           \
        _Pragma("unroll") for (int w = 0; w < 9; ++w) tot += cnts[t_ & 1][w];  \
        if (site) {                                                            \
            if ((tot < WCAP_) && (dep == 0) && (cm > THETA_)) {                \
                out[(((size_t)b * CO_ + ca) * NSITE + tid) * TP_ + t_] = 1.0f; \
                dep = FODEP_ - 1;                                              \
            } else {                                                           \
                dep = dep ? dep - 1 : 0;                                       \
            }                                                                  \
        }                                                                      \
    }

__launch_bounds__(576)
__global__ void k_wta(const float* __restrict__ m_in, const int* __restrict__ a_in,
                      float* __restrict__ out) {
    int b = blockIdx.x;
    int tid = threadIdx.x;
    int lane = tid & 63;
    int wid = tid >> 6;                 // 9 waves
    __shared__ int cnts[2][9];

    bool site = (tid < NSITE);
    const float* mb = m_in + (size_t)b * TP_ * NSITE;
    const int*   ab = a_in + (size_t)b * TP_ * NSITE;
    int dep = 0;

    float m0 = 0.f, m1 = 0.f, m2 = 0.f, m3 = 0.f;
    int   a0 = 0,   a1 = 0,   a2 = 0,   a3 = 0;
    if (site) {
        m0 = mb[0 * NSITE + tid]; a0 = ab[0 * NSITE + tid];
        m1 = mb[1 * NSITE + tid]; a1 = ab[1 * NSITE + tid];
        m2 = mb[2 * NSITE + tid]; a2 = ab[2 * NSITE + tid];
        m3 = mb[3 * NSITE + tid]; a3 = ab[3 * NSITE + tid];
    }

    for (int t = 0; t < TP_; t += 4) {
        WSTEP(m0, a0, t);
        if (t + 1 < TP_) WSTEP(m1, a1, t + 1);
        if (t + 2 < TP_) WSTEP(m2, a2, t + 2);
        if (t + 3 < TP_) WSTEP(m3, a3, t + 3);
    }
}

// ---------------- launcher ----------------
extern "C" void kernel_launch(void* const* d_in, const int* in_sizes, int n_in,
                              void* d_out, int out_size, void* d_ws, size_t ws_size,
                              hipStream_t stream) {
    const float* in     = (const float*)d_in[0];
    const float* weight = (const float*)d_in[1];
    const float* bias   = (const float*)d_in[2];
    float* out = (float*)d_out;

    float* wkf   = (float*)d_ws + WS_WKF;
    int*   kstab = (int*)((float*)d_ws + WS_KS);
    float* m     = (float*)d_ws + WS_M;
    int*   a     = (int*)((float*)d_ws + WS_A);

    k_wk<<<(CO_ * NTAP_ + 255) / 256, 256, 0, stream>>>(weight, wkf, kstab);
    k_conv<<<GRID_, 512, 0, stream>>>(in, wkf, kstab, bias, m, a, (float4*)out);
    k_wta<<<B_, 576, 0, stream>>>(m, a, out);
}